// Round 1
// baseline (20809.673 us; speedup 1.0000x reference)
//
#include <hip/hip_runtime.h>
#include <cstdint>
#include <cstring>

#define DIN 4096
#define DLAT 32768
#define NROW 4096
#define TOPK 64
#define NEG_INF (-3.402823466e38f)

typedef __attribute__((ext_vector_type(8))) short short8;
typedef __attribute__((ext_vector_type(4))) float floatx4;

static __device__ __forceinline__ float b2f(unsigned short s) {
    unsigned int u = ((unsigned int)s) << 16;
    float f;
    __builtin_memcpy(&f, &u, 4);
    return f;
}
static __device__ __forceinline__ unsigned short f2b(float f) {
    unsigned int u;
    __builtin_memcpy(&u, &f, 4);
    u = u + 0x7fffu + ((u >> 16) & 1u);  // RNE
    return (unsigned short)(u >> 16);
}

// ---------------------------------------------------------------------------
// K1: dead mask + n_dead
// ---------------------------------------------------------------------------
__global__ __launch_bounds__(1024) void mask_kernel(const int* __restrict__ steps,
                                                    const int* __restrict__ thrp,
                                                    float* __restrict__ dmask,
                                                    float* __restrict__ o_nd) {
    const int t = threadIdx.x;
    const int thr = thrp[0];
    int cnt = 0;
    for (int u = 0; u < DLAT / 1024; u++) {
        int l = u * 1024 + t;
        int d = (steps[l] >= thr) ? 1 : 0;
        dmask[l] = (float)d;
        cnt += d;
    }
    __shared__ int red[16];
#pragma unroll
    for (int off = 32; off > 0; off >>= 1) cnt += __shfl_down(cnt, off);
    if ((t & 63) == 0) red[t >> 6] = cnt;
    __syncthreads();
    if (t == 0) {
        int s = 0;
        for (int w = 0; w < 16; w++) s += red[w];
        o_nd[0] = (float)s;  // harness reads out buffer as fp32
    }
}

// ---------------------------------------------------------------------------
// K2: encoder GEMM, fp32 vector.  C[m,n] = sum_k (x[m,k]-b_pre[k])*We[n,k] + b_enc[n]
// 128x128 tile, BK=8, 256 threads, 8x8 per thread.
// ---------------------------------------------------------------------------
__global__ __launch_bounds__(256) void enc_gemm(const float* __restrict__ X,
                                                const float* __restrict__ We,
                                                const float* __restrict__ b_enc,
                                                const float* __restrict__ b_pre,
                                                float* __restrict__ out) {
    __shared__ __align__(16) float As[8][132];
    __shared__ __align__(16) float Bs[8][132];
    const int n0 = blockIdx.x * 128;
    const int m0 = blockIdx.y * 128;
    const int t = threadIdx.x;
    const int tx = t & 15, ty = t >> 4;
    const int ar = t >> 1, ac = (t & 1) * 4;

    float acc[8][8];
#pragma unroll
    for (int i = 0; i < 8; i++)
#pragma unroll
        for (int j = 0; j < 8; j++) acc[i][j] = 0.f;

    const float* Ag = X + (size_t)(m0 + ar) * DIN + ac;
    const float* Bg = We + (size_t)(n0 + ar) * DIN + ac;

    for (int k0 = 0; k0 < DIN; k0 += 8) {
        float4 av = *(const float4*)(Ag + k0);
        float4 pv = *(const float4*)(b_pre + k0 + ac);
        float4 bv = *(const float4*)(Bg + k0);
        av.x -= pv.x; av.y -= pv.y; av.z -= pv.z; av.w -= pv.w;
        __syncthreads();
        As[ac + 0][ar] = av.x; As[ac + 1][ar] = av.y;
        As[ac + 2][ar] = av.z; As[ac + 3][ar] = av.w;
        Bs[ac + 0][ar] = bv.x; Bs[ac + 1][ar] = bv.y;
        Bs[ac + 2][ar] = bv.z; Bs[ac + 3][ar] = bv.w;
        __syncthreads();
#pragma unroll
        for (int k = 0; k < 8; k++) {
            float a[8], b[8];
            *(float4*)&a[0] = *(const float4*)&As[k][ty * 8];
            *(float4*)&a[4] = *(const float4*)&As[k][ty * 8 + 4];
            *(float4*)&b[0] = *(const float4*)&Bs[k][tx * 8];
            *(float4*)&b[4] = *(const float4*)&Bs[k][tx * 8 + 4];
#pragma unroll
            for (int i = 0; i < 8; i++)
#pragma unroll
                for (int j = 0; j < 8; j++) acc[i][j] = fmaf(a[i], b[j], acc[i][j]);
        }
    }
    float4 be0 = *(const float4*)(b_enc + n0 + tx * 8);
    float4 be1 = *(const float4*)(b_enc + n0 + tx * 8 + 4);
#pragma unroll
    for (int i = 0; i < 8; i++) {
        float* op = out + (size_t)(m0 + ty * 8 + i) * DLAT + n0 + tx * 8;
        float4 o0 = make_float4(acc[i][0] + be0.x, acc[i][1] + be0.y,
                                acc[i][2] + be0.z, acc[i][3] + be0.w);
        float4 o1 = make_float4(acc[i][4] + be1.x, acc[i][5] + be1.y,
                                acc[i][6] + be1.z, acc[i][7] + be1.w);
        *(float4*)op = o0;
        *(float4*)(op + 4) = o1;
    }
}

// ---------------------------------------------------------------------------
// K3: per-row top-64 + ghost_sum + p_bf16 = bf16(exp(pre)*dmask)
// One block (1024 thr) per row; row lives in registers (32 vals/thread).
// ---------------------------------------------------------------------------
__global__ __launch_bounds__(1024) void topk_kernel(const float* __restrict__ pre,
                                                    const float* __restrict__ dmask,
                                                    unsigned short* __restrict__ p_out,
                                                    float* __restrict__ gsum,
                                                    float* __restrict__ topv,
                                                    int* __restrict__ topi) {
    const int n = blockIdx.x, t = threadIdx.x;
    const float* row = pre + (size_t)n * DLAT;
    unsigned short* prow = p_out + (size_t)n * DLAT;

    float v[32];
    float lsum = 0.f;
#pragma unroll
    for (int u = 0; u < 32; u++) {
        int l = u * 1024 + t;
        float val = row[l];
        v[u] = val;
        float e = expf(val) * dmask[l];
        lsum += e;
        prow[l] = f2b(e);
    }

    __shared__ float rv[16];
    __shared__ int ri[16];
    __shared__ int bgi;

    // ghost_sum reduce
#pragma unroll
    for (int off = 32; off > 0; off >>= 1) lsum += __shfl_down(lsum, off);
    if ((t & 63) == 0) rv[t >> 6] = lsum;
    __syncthreads();
    if (t == 0) {
        float s = 0.f;
        for (int w = 0; w < 16; w++) s += rv[w];
        gsum[n] = s;
    }
    __syncthreads();

    // local argmax (smallest index wins ties; within thread smaller u = smaller l)
    float lmax = NEG_INF;
    int larg = 0x7fffffff;
#pragma unroll
    for (int u = 0; u < 32; u++) {
        int l = u * 1024 + t;
        if (v[u] > lmax) { lmax = v[u]; larg = l; }
    }

    for (int it = 0; it < TOPK; it++) {
        float mv = lmax;
        int mi = larg;
#pragma unroll
        for (int off = 32; off > 0; off >>= 1) {
            float ov = __shfl_down(mv, off);
            int oi = __shfl_down(mi, off);
            if (ov > mv || (ov == mv && oi < mi)) { mv = ov; mi = oi; }
        }
        if ((t & 63) == 0) { rv[t >> 6] = mv; ri[t >> 6] = mi; }
        __syncthreads();
        if (t < 64) {
            mv = (t < 16) ? rv[t] : NEG_INF;
            mi = (t < 16) ? ri[t] : 0x7fffffff;
#pragma unroll
            for (int off = 8; off > 0; off >>= 1) {
                float ov = __shfl_down(mv, off);
                int oi = __shfl_down(mi, off);
                if (ov > mv || (ov == mv && oi < mi)) { mv = ov; mi = oi; }
            }
            if (t == 0) {
                bgi = mi;
                topv[(size_t)n * TOPK + it] = mv;
                topi[(size_t)n * TOPK + it] = mi;
            }
        }
        __syncthreads();
        int gi = bgi;
        if ((gi & 1023) == t) {  // owner removes element and recomputes local max
            int uu = gi >> 10;
#pragma unroll
            for (int u = 0; u < 32; u++)
                if (u == uu) v[u] = NEG_INF;
            lmax = NEG_INF;
            larg = 0x7fffffff;
#pragma unroll
            for (int u = 0; u < 32; u++) {
                int l = u * 1024 + t;
                if (v[u] > lmax) { lmax = v[u]; larg = l; }
            }
        }
    }
}

// ---------------------------------------------------------------------------
// K4: Wt[l][i] = bf16(W_dec[i][l])   (coalesced both sides via LDS tile)
// ---------------------------------------------------------------------------
__global__ __launch_bounds__(256) void transpose_wdec(const float* __restrict__ Wd,
                                                      unsigned short* __restrict__ Wt) {
    __shared__ float tile[32][33];
    const int l0 = blockIdx.x * 32, i0 = blockIdx.y * 32;
    const int c = threadIdx.x & 31, r = threadIdx.x >> 5;  // r in 0..7
#pragma unroll
    for (int rr = 0; rr < 4; rr++) {
        int i = i0 + r + rr * 8;
        tile[r + rr * 8][c] = Wd[(size_t)i * DLAT + l0 + c];
    }
    __syncthreads();
#pragma unroll
    for (int rr = 0; rr < 4; rr++) {
        int l = l0 + r + rr * 8;
        Wt[(size_t)l * DIN + i0 + c] = f2b(tile[c][r + rr * 8]);
    }
}

// ---------------------------------------------------------------------------
// K5: ghost GEMM (bf16 MFMA): xg_raw[n,i] = sum_l P[n,l] * Wt[l,i]
// 128x128 tile, BK=32, 4 waves (2x2), 4x4 subtiles of 16x16x32 per wave.
// ---------------------------------------------------------------------------
__global__ __launch_bounds__(256) void ghost_gemm(const unsigned short* __restrict__ P,
                                                  const unsigned short* __restrict__ Wt,
                                                  float* __restrict__ out) {
    __shared__ __align__(16) short As[128][32];  // [n_local][k_local]
    __shared__ __align__(16) short Bs[128][32];  // [i_local][k_local]
    const int i0 = blockIdx.x * 128, n0 = blockIdx.y * 128;
    const int t = threadIdx.x;
    const int w = t >> 6, lane = t & 63, lm = lane & 15, quad = lane >> 4;
    const int wm = w >> 1, wn = w & 1;

    floatx4 acc[4][4];
#pragma unroll
    for (int a = 0; a < 4; a++)
#pragma unroll
        for (int b = 0; b < 4; b++) acc[a][b] = (floatx4){0.f, 0.f, 0.f, 0.f};

    const int ar = t >> 1, ah = t & 1;  // A staging: row, 16-elem half
    const int br = t >> 3, bs = t & 7;  // B staging: l row (0..31), 16-elem seg
    const unsigned short* Ag = P + (size_t)(n0 + ar) * DLAT + ah * 16;
    const unsigned short* Bg = Wt + (size_t)br * DIN + i0 + bs * 16;

    for (int k0 = 0; k0 < DLAT; k0 += 32) {
        short8 a0 = *(const short8*)(Ag + k0);
        short8 a1 = *(const short8*)(Ag + k0 + 8);
        short8 b0 = *(const short8*)(Bg + (size_t)k0 * DIN);
        short8 b1 = *(const short8*)(Bg + (size_t)k0 * DIN + 8);
        __syncthreads();
        *(short8*)&As[ar][ah * 16] = a0;
        *(short8*)&As[ar][ah * 16 + 8] = a1;
#pragma unroll
        for (int j = 0; j < 8; j++) Bs[bs * 16 + j][br] = b0[j];
#pragma unroll
        for (int j = 0; j < 8; j++) Bs[bs * 16 + 8 + j][br] = b1[j];
        __syncthreads();

        short8 av[4], bv[4];
#pragma unroll
        for (int s = 0; s < 4; s++)
            av[s] = *(const short8*)&As[wm * 64 + s * 16 + lm][quad * 8];
#pragma unroll
        for (int s = 0; s < 4; s++)
            bv[s] = *(const short8*)&Bs[wn * 64 + s * 16 + lm][quad * 8];
#pragma unroll
        for (int sm = 0; sm < 4; sm++)
#pragma unroll
            for (int sn = 0; sn < 4; sn++)
                acc[sm][sn] = __builtin_amdgcn_mfma_f32_16x16x32_bf16(av[sm], bv[sn],
                                                                     acc[sm][sn], 0, 0, 0);
    }
    // C/D layout: col = lane&15, row = quad*4 + reg   [guide §3, m89/m91 verified]
#pragma unroll
    for (int sm = 0; sm < 4; sm++)
#pragma unroll
        for (int sn = 0; sn < 4; sn++) {
            int col = i0 + wn * 64 + sn * 16 + lm;
#pragma unroll
            for (int r = 0; r < 4; r++) {
                int rowi = n0 + wm * 64 + sm * 16 + quad * 4 + r;
                out[(size_t)rowi * DIN + col] = acc[sm][sn][r];
            }
        }
}

// ---------------------------------------------------------------------------
// K6: sparse decoder: x_hat[n,:] = b_dec + b_pre + sum_j relu(v_j) * Wt[idx_j,:]
// ---------------------------------------------------------------------------
__global__ __launch_bounds__(256) void sparse_decode(const float* __restrict__ topv,
                                                     const int* __restrict__ topi,
                                                     const unsigned short* __restrict__ Wt,
                                                     const float* __restrict__ b_dec,
                                                     const float* __restrict__ b_pre,
                                                     float* __restrict__ out) {
    const int n = blockIdx.x, t = threadIdx.x;
    __shared__ float sv[TOPK];
    __shared__ int si[TOPK];
    if (t < TOPK) {
        sv[t] = fmaxf(topv[(size_t)n * TOPK + t], 0.f);
        si[t] = topi[(size_t)n * TOPK + t];
    }
    __syncthreads();
    const int ib = t * 16;
    float acc[16];
#pragma unroll
    for (int u = 0; u < 16; u++) acc[u] = b_dec[ib + u] + b_pre[ib + u];
    for (int j = 0; j < TOPK; j++) {
        float vj = sv[j];
        const unsigned short* wr = Wt + (size_t)si[j] * DIN + ib;
        short8 w0 = *(const short8*)(wr);
        short8 w1 = *(const short8*)(wr + 8);
#pragma unroll
        for (int u = 0; u < 8; u++) acc[u] = fmaf(vj, b2f((unsigned short)w0[u]), acc[u]);
#pragma unroll
        for (int u = 0; u < 8; u++) acc[u + 8] = fmaf(vj, b2f((unsigned short)w1[u]), acc[u + 8]);
    }
    float* op = out + (size_t)n * DIN + ib;
#pragma unroll
    for (int u = 0; u < 16; u += 4)
        *(float4*)(op + u) = make_float4(acc[u], acc[u + 1], acc[u + 2], acc[u + 3]);
}

// ---------------------------------------------------------------------------
// K7: per-row norms + final scaling of x_ghost, ghost_tgt
// ---------------------------------------------------------------------------
__global__ __launch_bounds__(256) void finalize_kernel(const float* __restrict__ X,
                                                       const float* __restrict__ xhat,
                                                       const float* __restrict__ gsum,
                                                       float* __restrict__ gh,
                                                       float* __restrict__ tgt) {
    const int n = blockIdx.x, t = threadIdx.x;
    const float* xr = X + (size_t)n * DIN;
    const float* hr = xhat + (size_t)n * DIN;
    float* gr = gh + (size_t)n * DIN;
    float* tr = tgt + (size_t)n * DIN;
    float sr = 0.f, sg = 0.f;
    for (int i = t; i < DIN; i += 256) {
        float d = xr[i] - hr[i];
        sr += d * d;
        float g = gr[i];
        sg += g * g;
    }
    __shared__ float r1[4], r2[4];
    __shared__ float sca;
#pragma unroll
    for (int off = 32; off > 0; off >>= 1) {
        sr += __shfl_down(sr, off);
        sg += __shfl_down(sg, off);
    }
    if ((t & 63) == 0) { r1[t >> 6] = sr; r2[t >> 6] = sg; }
    __syncthreads();
    if (t == 0) {
        float ssr = r1[0] + r1[1] + r1[2] + r1[3];
        float ssg = r2[0] + r2[1] + r2[2] + r2[3];
        float gs = fmaxf(gsum[n], 1e-8f);               // clip(sum, 1e-8)
        float gn = fmaxf(sqrtf(ssg) / gs, 1e-8f);       // clip(||x_ghost||, 1e-8)
        sca = 0.5f * sqrtf(ssr) / (gs * gn);            // xg_raw * sca == x_ghost_sc
    }
    __syncthreads();
    float s = sca;
    for (int i = t; i < DIN; i += 256) {
        gr[i] = gr[i] * s;
        tr[i] = 0.5f * (xr[i] - hr[i]);
    }
}

// ---------------------------------------------------------------------------
// K8: scatter relu(topv) into zeroed z
// ---------------------------------------------------------------------------
__global__ __launch_bounds__(64) void z_scatter(const float* __restrict__ topv,
                                                const int* __restrict__ topi,
                                                float* __restrict__ z) {
    const int n = blockIdx.x, t = threadIdx.x;
    float v = topv[(size_t)n * TOPK + t];
    int ix = topi[(size_t)n * TOPK + t];
    z[(size_t)n * DLAT + ix] = fmaxf(v, 0.f);
}

// ---------------------------------------------------------------------------
extern "C" void kernel_launch(void* const* d_in, const int* in_sizes, int n_in,
                              void* d_out, int out_size, void* d_ws, size_t ws_size,
                              hipStream_t stream) {
    const float* x = (const float*)d_in[0];
    const float* We = (const float*)d_in[1];
    const float* b_enc = (const float*)d_in[2];
    const float* Wd = (const float*)d_in[3];
    const float* b_dec = (const float*)d_in[4];
    const float* b_pre = (const float*)d_in[5];
    const int* steps = (const int*)d_in[6];
    const int* thr = (const int*)d_in[7];

    float* o_pre = (float*)d_out;
    float* o_z = o_pre + (size_t)NROW * DLAT;
    float* o_xhat = o_z + (size_t)NROW * DLAT;
    float* o_gh = o_xhat + (size_t)NROW * DIN;
    float* o_tgt = o_gh + (size_t)NROW * DIN;
    float* o_nd = o_tgt + (size_t)NROW * DIN;

    // scratch aliased into the z output region (finalized last):
    //   [0, 256MB)   p_bf16 [NROW][DLAT]
    //   [256, 512MB) Wt bf16 [DLAT][DIN]
    unsigned short* p_bf = (unsigned short*)o_z;
    unsigned short* Wt = p_bf + (size_t)NROW * DLAT;

    float* ws_dmask = (float*)d_ws;               // 32768
    float* ws_gsum = ws_dmask + DLAT;             // 4096
    float* ws_topv = ws_gsum + NROW;              // 4096*64
    int* ws_topi = (int*)(ws_topv + (size_t)NROW * TOPK);  // 4096*64

    hipLaunchKernelGGL(mask_kernel, dim3(1), dim3(1024), 0, stream, steps, thr, ws_dmask, o_nd);
    hipLaunchKernelGGL(enc_gemm, dim3(DLAT / 128, NROW / 128), dim3(256), 0, stream,
                       x, We, b_enc, b_pre, o_pre);
    hipLaunchKernelGGL(topk_kernel, dim3(NROW), dim3(1024), 0, stream,
                       o_pre, ws_dmask, p_bf, ws_gsum, ws_topv, ws_topi);
    hipLaunchKernelGGL(transpose_wdec, dim3(DLAT / 32, DIN / 32), dim3(256), 0, stream, Wd, Wt);
    hipLaunchKernelGGL(ghost_gemm, dim3(DIN / 128, NROW / 128), dim3(256), 0, stream,
                       p_bf, Wt, o_gh);
    hipLaunchKernelGGL(sparse_decode, dim3(NROW), dim3(256), 0, stream,
                       ws_topv, ws_topi, Wt, b_dec, b_pre, o_xhat);
    hipLaunchKernelGGL(finalize_kernel, dim3(NROW), dim3(256), 0, stream,
                       x, o_xhat, ws_gsum, o_gh, o_tgt);
    // z region is free of scratch consumers now: zero it and scatter the top-k
    hipMemsetAsync(o_z, 0, (size_t)NROW * DLAT * sizeof(float), stream);
    hipLaunchKernelGGL(z_scatter, dim3(NROW), dim3(64), 0, stream, ws_topv, ws_topi, o_z);
}